// Round 1
// baseline (2107.760 us; speedup 1.0000x reference)
//
#include <hip/hip_runtime.h>
#include <hip/hip_cooperative_groups.h>
#include <stdint.h>

namespace cg = cooperative_groups;

// LSTM decoder: VOCAB=32000, EMBED=512, HIDDEN=1024, B=32, S=48.
// Plan:
//   1. cast W_ih, W_hh, fc_W, hidden -> bf16 (ws)
//   2. gather X[s][b][:] = emb[inputs[b][s]] as bf16
//   3. GEMM1: Xg[1536,4096] = X @ W_ih^T + b_ih + b_hh   (fp32 out)
//   4. ONE persistent cooperative kernel runs all 48 LSTM steps with
//      grid.sync() between steps (removes ~48x launch+ramp overhead;
//      Whh slice stays L1/L2-hot since WGs never migrate)
//   5. GEMM2: out[b][s][v] = H_all[1..48] @ fc_W^T + fc_b (fp32 out, scatter)
// GEMM block order: m-fastest + XCD-chunked remap so the 12 m-tiles that
// share one B-panel run consecutively on the same XCD's L2 (B re-fetch was
// 6x = 402 MB FETCH_SIZE with the default x-fastest order).

typedef unsigned short u16;
typedef __attribute__((ext_vector_type(8))) short bf16x8;
typedef __attribute__((ext_vector_type(4))) float floatx4;
struct alignas(8) us4 { u16 x, y, z, w; };

#define BATCH 32
#define SEQ   48
#define EMBED 512
#define HID   1024
#define VOCAB 32000
#define MROWS (SEQ * BATCH)   // 1536

__device__ __forceinline__ u16 f2bf(float f) {
  unsigned u = __float_as_uint(f);
  u += 0x7FFF + ((u >> 16) & 1);   // round-to-nearest-even
  return (u16)(u >> 16);
}

__device__ __forceinline__ floatx4 mfma16(bf16x8 a, bf16x8 b, floatx4 c) {
  return __builtin_amdgcn_mfma_f32_16x16x32_bf16(a, b, c, 0, 0, 0);
}

// async global->LDS, 16B per lane; lds base must be wave-uniform
typedef __attribute__((address_space(1))) unsigned int as1_uint;
typedef __attribute__((address_space(3))) unsigned int as3_uint;
__device__ __forceinline__ void gl_lds16(const void* g, void* l) {
  __builtin_amdgcn_global_load_lds((as1_uint*)g, (as3_uint*)l, 16, 0, 0);
}

__device__ __forceinline__ float sigmoidf_(float x) {
  return 1.0f / (1.0f + __expf(-x));
}

// ---------------- cast fp32 -> bf16, 4 elems/thread, n % 4 == 0 ----------------
__global__ void cast_kernel(const float* __restrict__ in, u16* __restrict__ out, int n4) {
  int i = blockIdx.x * blockDim.x + threadIdx.x;
  if (i < n4) {
    float4 v = *(const float4*)(in + (size_t)i * 4);
    us4 o;
    o.x = f2bf(v.x); o.y = f2bf(v.y); o.z = f2bf(v.z); o.w = f2bf(v.w);
    *(us4*)(out + (size_t)i * 4) = o;
  }
}

// ---------------- embedding gather: X[s*32+b][:] = bf16(emb[idx[b][s]]) --------
__global__ void gather_kernel(const int* __restrict__ idx, const float* __restrict__ emb,
                              u16* __restrict__ X) {
  int bid = blockIdx.x;          // = s*32 + b
  int s = bid >> 5, b = bid & 31;
  int t = idx[b * SEQ + s];
  const float* src = emb + (size_t)t * EMBED;
  u16* dst = X + (size_t)bid * EMBED;
  int e = threadIdx.x * 4;       // 128 threads * 4 = 512
  float4 v = *(const float4*)(src + e);
  us4 o;
  o.x = f2bf(v.x); o.y = f2bf(v.y); o.z = f2bf(v.z); o.w = f2bf(v.w);
  *(us4*)(dst + e) = o;
}

// ---------------- tiled bf16 GEMM: C = A[M,K] @ B[N,K]^T + bias ----------------
// 128x128 tile, BK=64, 4 waves, each wave 64x64 via 4x4 16x16x32 MFMA tiles.
// LDS chunks (16B) XOR-swizzled by row to avoid ds_read_b128 bank conflicts;
// swizzle is applied to the per-lane GLOBAL address so global_load_lds's
// wave-uniform-base + lane*16 LDS destination stays contiguous.
// Block-order remap: work ids are m-fastest (consecutive works share the
// B-panel) and XCD-chunked (work = (lid%8)*per + lid/8), so each XCD's L2
// serves the 12 m-tiles of a B-panel from one fetch. Requires nwg%8==0
// (384 and 3000 both qualify); falls back to identity otherwise.
// out_mode 0: C[m*N + n]   (row-major)
// out_mode 1: C[(b*SEQ + s)*N + n] with b=m&31, s=m>>5  (logits scatter)
__global__ __launch_bounds__(256) void gemm_bt_kernel(
    const u16* __restrict__ A, const u16* __restrict__ B,
    const float* __restrict__ bias0, const float* __restrict__ bias1,
    float* __restrict__ C, int M, int N, int K, int out_mode) {
  __shared__ u16 As[128 * 64];   // row r: 8 chunks of 8 bf16; chunk p holds global chunk p^(r&7)
  __shared__ u16 Bs[128 * 64];

  const int tid = threadIdx.x;
  const int wave = tid >> 6, lane = tid & 63;
  const int l3 = lane >> 3, l7 = lane & 7;
  const int q = lane >> 4, rf = lane & 15;

  // ---- XCD-aware, B-panel-reuse block remap ----
  const int mt = gridDim.y;                    // # of m-tiles (12)
  const int nwg = gridDim.x * mt;
  int lid = blockIdx.y * gridDim.x + blockIdx.x;
  int work;
  if ((nwg & 7) == 0) {
    int per = nwg >> 3;
    work = (lid & 7) * per + (lid >> 3);       // XCD-chunked (bijective)
  } else {
    work = lid;
  }
  const int tn = work / mt, tm = work % mt;    // m-fastest: share B-panel

  const int gm0 = tm * 128, gn0 = tn * 128;
  const int wm = (wave & 1) * 64, wn = (wave >> 1) * 64;

  floatx4 acc[4][4];
#pragma unroll
  for (int i = 0; i < 4; ++i)
#pragma unroll
    for (int j = 0; j < 4; ++j) acc[i][j] = (floatx4){0.f, 0.f, 0.f, 0.f};

  for (int k0 = 0; k0 < K; k0 += 64) {
    // stage: 16 wave-issues each cover 8 rows x 8 chunks (1 KiB LDS)
#pragma unroll
    for (int i = 0; i < 4; ++i) {
      int e = wave * 4 + i;
      int r = e * 8 + l3;
      int qd = l7 ^ (r & 7);
      gl_lds16(A + (size_t)(gm0 + r) * K + k0 + qd * 8, (void*)(As + e * 512));
      gl_lds16(B + (size_t)(gn0 + r) * K + k0 + qd * 8, (void*)(Bs + e * 512));
    }
    __syncthreads();   // compiler emits vmcnt(0) drain before barrier

#pragma unroll
    for (int kk = 0; kk < 64; kk += 32) {
      int jc = (kk >> 3) + q;   // global 16B chunk index for this quad
      bf16x8 af[4], bf[4];
#pragma unroll
      for (int mi = 0; mi < 4; ++mi) {
        int r = wm + mi * 16 + rf;
        af[mi] = *(const bf16x8*)(As + r * 64 + (jc ^ (r & 7)) * 8);
      }
#pragma unroll
      for (int ni = 0; ni < 4; ++ni) {
        int r = wn + ni * 16 + rf;
        bf[ni] = *(const bf16x8*)(Bs + r * 64 + (jc ^ (r & 7)) * 8);
      }
#pragma unroll
      for (int mi = 0; mi < 4; ++mi)
#pragma unroll
        for (int ni = 0; ni < 4; ++ni)
          acc[mi][ni] = mfma16(af[mi], bf[ni], acc[mi][ni]);
    }
    __syncthreads();
  }

  // epilogue: D row = q*4 + reg (m), col = lane&15 (n)
#pragma unroll
  for (int ni = 0; ni < 4; ++ni) {
    int n = gn0 + wn + ni * 16 + rf;
    float bv = bias0[n];
    if (bias1) bv += bias1[n];
#pragma unroll
    for (int mi = 0; mi < 4; ++mi) {
#pragma unroll
      for (int r = 0; r < 4; ++r) {
        int m = gm0 + wm + mi * 16 + q * 4 + r;
        float val = acc[mi][ni][r] + bv;
        if (out_mode == 0) {
          C[(size_t)m * N + n] = val;
        } else {
          int b = m & 31, s = m >> 5;
          C[((size_t)b * SEQ + s) * N + n] = val;
        }
      }
    }
  }
}

// ---------------- one LSTM time step (fallback path only) ----------------------
__global__ __launch_bounds__(256) void lstm_step_kernel(
    const u16* __restrict__ h_prev,   // [32][1024] bf16
    const u16* __restrict__ Whh,      // [4096][1024] bf16
    const float* __restrict__ xg,     // [32][4096] fp32 (input gates + biases)
    const float* __restrict__ c_in,   // [32][1024] fp32
    float* __restrict__ c_out,        // [32][1024] fp32
    u16* __restrict__ h_out) {        // [32][1024] bf16
  const int u0 = blockIdx.x * 4;
  const int tid = threadIdx.x;
  const int wave = tid >> 6, lane = tid & 63;
  const int q = lane >> 4, rf = lane & 15;
  const int gate = rf >> 2, du = rf & 3;
  const int brow = gate * HID + u0 + du;      // W_hh row for this lane's n-index

  floatx4 acc0 = {0.f, 0.f, 0.f, 0.f}, acc1 = {0.f, 0.f, 0.f, 0.f};
  const u16* wp = Whh + (size_t)brow * HID + wave * 256 + q * 8;
  const u16* a0p = h_prev + (size_t)rf * HID + wave * 256 + q * 8;
  const u16* a1p = a0p + 16 * HID;
#pragma unroll
  for (int ks = 0; ks < 256; ks += 32) {
    bf16x8 bv = *(const bf16x8*)(wp + ks);
    bf16x8 a0 = *(const bf16x8*)(a0p + ks);
    bf16x8 a1 = *(const bf16x8*)(a1p + ks);
    acc0 = mfma16(a0, bv, acc0);
    acc1 = mfma16(a1, bv, acc1);
  }

  __shared__ float red[4][32][16];   // [wave][batch][n]
#pragma unroll
  for (int r = 0; r < 4; ++r) {
    red[wave][q * 4 + r][rf] = acc0[r];
    red[wave][16 + q * 4 + r][rf] = acc1[r];
  }
  __syncthreads();

  if (tid < 128) {
    int b = tid >> 2, d = tid & 3;
    int u = u0 + d;
    float g4[4];
#pragma unroll
    for (int gt = 0; gt < 4; ++gt) {
      int n = gt * 4 + d;
      float v = red[0][b][n] + red[1][b][n] + red[2][b][n] + red[3][b][n];
      v += xg[b * 4096 + gt * HID + u];
      g4[gt] = v;
    }
    float i_ = sigmoidf_(g4[0]);
    float f_ = sigmoidf_(g4[1]);
    float gg = tanhf(g4[2]);
    float o_ = sigmoidf_(g4[3]);
    float c = f_ * c_in[b * HID + u] + i_ * gg;
    float h = o_ * tanhf(c);
    c_out[b * HID + u] = c;
    h_out[b * HID + u] = f2bf(h);
  }
}

// ---------------- persistent LSTM: all 48 steps in one cooperative kernel ------
// 256 WGs x 256 thr (1 WG/CU). WG g owns hidden units u0=4g; per-WG work per
// step is identical to lstm_step_kernel (4 waves split K=1024, LDS reduce).
// c state lives in registers of the 128 activation threads (fp32, like c_ws).
// Whh slice (32KB/WG) is read from global each step but stays L1/L2-hot since
// WGs never migrate. h goes through global (Hall) with grid.sync() between
// steps for cross-XCD visibility.
__global__ __launch_bounds__(256, 1) void lstm_persist_kernel(
    const u16* __restrict__ Whh,      // [4096][1024] bf16
    const float* __restrict__ xg_all, // [48][32][4096] fp32
    const float* __restrict__ c_init, // [32][1024] fp32
    u16* __restrict__ Hall) {         // [49][32][1024] bf16, slot 0 prefilled
  cg::grid_group grid = cg::this_grid();

  const int u0 = blockIdx.x * 4;
  const int tid = threadIdx.x;
  const int wave = tid >> 6, lane = tid & 63;
  const int q = lane >> 4, rf = lane & 15;
  const int gate = rf >> 2, du = rf & 3;
  const int brow = gate * HID + u0 + du;

  __shared__ float red[4][32][16];   // [wave][batch][n]

  // activation-thread state: (batch ab, unit u0+ad), c in fp32 register
  const int ab = tid >> 2, ad = tid & 3;
  float c_reg = 0.f;
  if (tid < 128) c_reg = c_init[ab * HID + u0 + ad];

  const u16* wp = Whh + (size_t)brow * HID + wave * 256 + q * 8;

  for (int s = 0; s < SEQ; ++s) {
    const u16* h_prev = Hall + (size_t)s * BATCH * HID;
    const float* xg = xg_all + (size_t)s * BATCH * 4096;
    const u16* a0p = h_prev + (size_t)rf * HID + wave * 256 + q * 8;
    const u16* a1p = a0p + 16 * HID;

    floatx4 acc0 = {0.f, 0.f, 0.f, 0.f}, acc1 = {0.f, 0.f, 0.f, 0.f};
#pragma unroll
    for (int ks = 0; ks < 256; ks += 32) {
      bf16x8 bv = *(const bf16x8*)(wp + ks);
      bf16x8 a0 = *(const bf16x8*)(a0p + ks);
      bf16x8 a1 = *(const bf16x8*)(a1p + ks);
      acc0 = mfma16(a0, bv, acc0);
      acc1 = mfma16(a1, bv, acc1);
    }

#pragma unroll
    for (int r = 0; r < 4; ++r) {
      red[wave][q * 4 + r][rf] = acc0[r];
      red[wave][16 + q * 4 + r][rf] = acc1[r];
    }
    __syncthreads();

    if (tid < 128) {
      float g4[4];
#pragma unroll
      for (int gt = 0; gt < 4; ++gt) {
        int n = gt * 4 + ad;
        float v = red[0][ab][n] + red[1][ab][n] + red[2][ab][n] + red[3][ab][n];
        v += xg[ab * 4096 + gt * HID + u0 + ad];
        g4[gt] = v;
      }
      float i_ = sigmoidf_(g4[0]);
      float f_ = sigmoidf_(g4[1]);
      float gg = tanhf(g4[2]);
      float o_ = sigmoidf_(g4[3]);
      c_reg = f_ * c_reg + i_ * gg;
      float h = o_ * tanhf(c_reg);
      Hall[(size_t)(s + 1) * BATCH * HID + ab * HID + u0 + ad] = f2bf(h);
    }
    grid.sync();   // includes block barrier -> red[] reuse next iter is safe
  }
}

extern "C" void kernel_launch(void* const* d_in, const int* in_sizes, int n_in,
                              void* d_out, int out_size, void* d_ws, size_t ws_size,
                              hipStream_t stream) {
  const int*   inputs = (const int*)d_in[0];
  const float* hidden = (const float*)d_in[1];
  const float* cell   = (const float*)d_in[2];
  const float* emb    = (const float*)d_in[3];
  const float* W_ih   = (const float*)d_in[4];
  const float* W_hh   = (const float*)d_in[5];
  const float* b_ih   = (const float*)d_in[6];
  const float* b_hh   = (const float*)d_in[7];
  const float* fc_W   = (const float*)d_in[8];
  const float* fc_b   = (const float*)d_in[9];
  float* out = (float*)d_out;

  char* ws = (char*)d_ws;
  // workspace layout (all 256B aligned), total ~108 MiB
  u16*   Xbf  = (u16*)(ws);                                  // 1536*512   bf16 = 1,572,864 B
  u16*   Wihb = (u16*)(ws + 1572864);                        // 4096*512   bf16 = 4,194,304 B
  u16*   Whhb = (u16*)(ws + 1572864 + 4194304);              // 4096*1024  bf16 = 8,388,608 B
  u16*   fcWb = (u16*)(ws + 14155776);                       // 32000*1024 bf16 = 65,536,000 B
  float* Xg   = (float*)(ws + 14155776 + 65536000);          // 1536*4096  f32  = 25,165,824 B
  u16*   Hall = (u16*)(ws + 104857600);                      // 49*32*1024 bf16 = 3,211,264 B
  float* c_ws = (float*)(ws + 104857600 + 3211264);          // 32*1024    f32  = 131,072 B

  // 1) casts to bf16
  cast_kernel<<<(4096 * 512 / 4 + 255) / 256, 256, 0, stream>>>(W_ih, Wihb, 4096 * 512 / 4);
  cast_kernel<<<(4096 * 1024 / 4 + 255) / 256, 256, 0, stream>>>(W_hh, Whhb, 4096 * 1024 / 4);
  cast_kernel<<<(VOCAB * 1024 / 4 + 255) / 256, 256, 0, stream>>>(fc_W, fcWb, VOCAB * 1024 / 4);
  cast_kernel<<<(BATCH * HID / 4 + 255) / 256, 256, 0, stream>>>(hidden, Hall, BATCH * HID / 4); // h0 -> slot 0

  // 2) embedding gather (time-major)
  gather_kernel<<<MROWS, 128, 0, stream>>>(inputs, emb, Xbf);

  // 3) GEMM1: Xg = X @ W_ih^T + b_ih + b_hh
  gemm_bt_kernel<<<dim3(4096 / 128, MROWS / 128), 256, 0, stream>>>(
      Xbf, Wihb, b_ih, b_hh, Xg, MROWS, 4096, EMBED, 0);

  // 4) all 48 recurrent steps in ONE persistent cooperative kernel
  {
    const u16*   whh_p  = Whhb;
    const float* xg_p   = Xg;
    const float* c_p    = cell;
    u16*         hall_p = Hall;
    void* kargs[] = {(void*)&whh_p, (void*)&xg_p, (void*)&c_p, (void*)&hall_p};
    hipError_t cerr = hipLaunchCooperativeKernel(
        reinterpret_cast<const void*>(&lstm_persist_kernel),
        dim3(256), dim3(256), kargs, 0, stream);
    if (cerr != hipSuccess) {
      // fallback: 48 sequential per-step launches (previous verified path)
      for (int s = 0; s < SEQ; ++s) {
        lstm_step_kernel<<<256, 256, 0, stream>>>(
            Hall + (size_t)s * BATCH * HID, Whhb, Xg + (size_t)s * BATCH * 4096,
            (s == 0) ? cell : c_ws, c_ws, Hall + (size_t)(s + 1) * BATCH * HID);
      }
    }
  }

  // 5) GEMM2: logits = H_all[1..48] @ fc_W^T + fc_b, scattered to [B][S][V]
  gemm_bt_kernel<<<dim3(VOCAB / 128, MROWS / 128), 256, 0, stream>>>(
      Hall + (size_t)BATCH * HID, fcWb, fc_b, (const float*)nullptr, out,
      MROWS, VOCAB, HID, 1);
}

// Round 2
// 980.970 us; speedup vs baseline: 2.1486x; 2.1486x over previous
//
#include <hip/hip_runtime.h>
#include <stdint.h>

// LSTM decoder: VOCAB=32000, EMBED=512, HIDDEN=1024, B=32, S=48.
// Plan:
//   1. cast W_ih, W_hh, fc_W, hidden -> bf16 (ws)
//   2. gather X[s][b][:] = emb[inputs[b][s]] as bf16 (+ zero barrier counter)
//   3. GEMM1: Xg[1536,4096] = X @ W_ih^T + b_ih + b_hh   (fp32 out)
//   4. ONE persistent kernel runs all 48 LSTM steps with a hand-rolled
//      monotonic-counter barrier (relaxed agent atomics, no cache
//      invalidation — cg::grid.sync cost 33us/step in round 1).
//      h exchange is made XCD-coherent explicitly: writers use sc0/sc1
//      write-through atomic u32 stores, readers use inline-asm
//      global_load_dwordx4 sc0 sc1 (read at the coherence point).
//   5. GEMM2: out[b][s][v] = H_all[1..48] @ fc_W^T + fc_b (fp32 out, scatter)

typedef unsigned short u16;
typedef __attribute__((ext_vector_type(8))) short bf16x8;
typedef __attribute__((ext_vector_type(4))) float floatx4;
struct alignas(8) us4 { u16 x, y, z, w; };

#define BATCH 32
#define SEQ   48
#define EMBED 512
#define HID   1024
#define VOCAB 32000
#define MROWS (SEQ * BATCH)   // 1536

__device__ __forceinline__ u16 f2bf(float f) {
  unsigned u = __float_as_uint(f);
  u += 0x7FFF + ((u >> 16) & 1);   // round-to-nearest-even
  return (u16)(u >> 16);
}

__device__ __forceinline__ floatx4 mfma16(bf16x8 a, bf16x8 b, floatx4 c) {
  return __builtin_amdgcn_mfma_f32_16x16x32_bf16(a, b, c, 0, 0, 0);
}

// async global->LDS, 16B per lane; lds base must be wave-uniform
typedef __attribute__((address_space(1))) unsigned int as1_uint;
typedef __attribute__((address_space(3))) unsigned int as3_uint;
__device__ __forceinline__ void gl_lds16(const void* g, void* l) {
  __builtin_amdgcn_global_load_lds((as1_uint*)g, (as3_uint*)l, 16, 0, 0);
}

__device__ __forceinline__ float sigmoidf_(float x) {
  return 1.0f / (1.0f + __expf(-x));
}

// coherent 16B load: bypass L1/L2, read at coherence point (IF$).
// No waitcnt inside — caller batches issues then drains once (rule #18:
// manual "s_waitcnt" + sched_barrier(0) before any consumer).
__device__ __forceinline__ void ld_c16(bf16x8& d, const u16* p) {
  asm volatile("global_load_dwordx4 %0, %1, off sc0 sc1" : "=&v"(d) : "v"(p));
}
// plain cached 16B load, same batched-issue pattern
__device__ __forceinline__ void ld_n16(bf16x8& d, const u16* p) {
  asm volatile("global_load_dwordx4 %0, %1, off" : "=&v"(d) : "v"(p));
}

// ---------------- cast fp32 -> bf16, 4 elems/thread, n % 4 == 0 ----------------
__global__ void cast_kernel(const float* __restrict__ in, u16* __restrict__ out, int n4) {
  int i = blockIdx.x * blockDim.x + threadIdx.x;
  if (i < n4) {
    float4 v = *(const float4*)(in + (size_t)i * 4);
    us4 o;
    o.x = f2bf(v.x); o.y = f2bf(v.y); o.z = f2bf(v.z); o.w = f2bf(v.w);
    *(us4*)(out + (size_t)i * 4) = o;
  }
}

// ---------------- embedding gather: X[s*32+b][:] = bf16(emb[idx[b][s]]) --------
// also zeroes the persistent-LSTM barrier counter (graph replays reuse ws!)
__global__ void gather_kernel(const int* __restrict__ idx, const float* __restrict__ emb,
                              u16* __restrict__ X, unsigned* __restrict__ bar) {
  int bid = blockIdx.x;          // = s*32 + b
  if (bid == 0 && threadIdx.x == 0) *bar = 0u;
  int s = bid >> 5, b = bid & 31;
  int t = idx[b * SEQ + s];
  const float* src = emb + (size_t)t * EMBED;
  u16* dst = X + (size_t)bid * EMBED;
  int e = threadIdx.x * 4;       // 128 threads * 4 = 512
  float4 v = *(const float4*)(src + e);
  us4 o;
  o.x = f2bf(v.x); o.y = f2bf(v.y); o.z = f2bf(v.z); o.w = f2bf(v.w);
  *(us4*)(dst + e) = o;
}

// ---------------- tiled bf16 GEMM: C = A[M,K] @ B[N,K]^T + bias ----------------
// 128x128 tile, BK=64, 4 waves, each wave 64x64 via 4x4 16x16x32 MFMA tiles.
// LDS chunks (16B) XOR-swizzled by row to avoid ds_read_b128 bank conflicts;
// swizzle is applied to the per-lane GLOBAL address so global_load_lds's
// wave-uniform-base + lane*16 LDS destination stays contiguous.
// Block-order remap: work ids are m-fastest (consecutive works share the
// B-panel) and XCD-chunked (work = (lid%8)*per + lid/8), so each XCD's L2
// serves the 12 m-tiles of a B-panel from one fetch. Requires nwg%8==0
// (384 and 3000 both qualify); falls back to identity otherwise.
// out_mode 0: C[m*N + n]   (row-major)
// out_mode 1: C[(b*SEQ + s)*N + n] with b=m&31, s=m>>5  (logits scatter)
__global__ __launch_bounds__(256) void gemm_bt_kernel(
    const u16* __restrict__ A, const u16* __restrict__ B,
    const float* __restrict__ bias0, const float* __restrict__ bias1,
    float* __restrict__ C, int M, int N, int K, int out_mode) {
  __shared__ u16 As[128 * 64];   // row r: 8 chunks of 8 bf16; chunk p holds global chunk p^(r&7)
  __shared__ u16 Bs[128 * 64];

  const int tid = threadIdx.x;
  const int wave = tid >> 6, lane = tid & 63;
  const int l3 = lane >> 3, l7 = lane & 7;
  const int q = lane >> 4, rf = lane & 15;

  // ---- XCD-aware, B-panel-reuse block remap ----
  const int mt = gridDim.y;                    // # of m-tiles (12)
  const int nwg = gridDim.x * mt;
  int lid = blockIdx.y * gridDim.x + blockIdx.x;
  int work;
  if ((nwg & 7) == 0) {
    int per = nwg >> 3;
    work = (lid & 7) * per + (lid >> 3);       // XCD-chunked (bijective)
  } else {
    work = lid;
  }
  const int tn = work / mt, tm = work % mt;    // m-fastest: share B-panel

  const int gm0 = tm * 128, gn0 = tn * 128;
  const int wm = (wave & 1) * 64, wn = (wave >> 1) * 64;

  floatx4 acc[4][4];
#pragma unroll
  for (int i = 0; i < 4; ++i)
#pragma unroll
    for (int j = 0; j < 4; ++j) acc[i][j] = (floatx4){0.f, 0.f, 0.f, 0.f};

  for (int k0 = 0; k0 < K; k0 += 64) {
    // stage: 16 wave-issues each cover 8 rows x 8 chunks (1 KiB LDS)
#pragma unroll
    for (int i = 0; i < 4; ++i) {
      int e = wave * 4 + i;
      int r = e * 8 + l3;
      int qd = l7 ^ (r & 7);
      gl_lds16(A + (size_t)(gm0 + r) * K + k0 + qd * 8, (void*)(As + e * 512));
      gl_lds16(B + (size_t)(gn0 + r) * K + k0 + qd * 8, (void*)(Bs + e * 512));
    }
    __syncthreads();   // compiler emits vmcnt(0) drain before barrier

#pragma unroll
    for (int kk = 0; kk < 64; kk += 32) {
      int jc = (kk >> 3) + q;   // global 16B chunk index for this quad
      bf16x8 af[4], bf[4];
#pragma unroll
      for (int mi = 0; mi < 4; ++mi) {
        int r = wm + mi * 16 + rf;
        af[mi] = *(const bf16x8*)(As + r * 64 + (jc ^ (r & 7)) * 8);
      }
#pragma unroll
      for (int ni = 0; ni < 4; ++ni) {
        int r = wn + ni * 16 + rf;
        bf[ni] = *(const bf16x8*)(Bs + r * 64 + (jc ^ (r & 7)) * 8);
      }
#pragma unroll
      for (int mi = 0; mi < 4; ++mi)
#pragma unroll
        for (int ni = 0; ni < 4; ++ni)
          acc[mi][ni] = mfma16(af[mi], bf[ni], acc[mi][ni]);
    }
    __syncthreads();
  }

  // epilogue: D row = q*4 + reg (m), col = lane&15 (n)
#pragma unroll
  for (int ni = 0; ni < 4; ++ni) {
    int n = gn0 + wn + ni * 16 + rf;
    float bv = bias0[n];
    if (bias1) bv += bias1[n];
#pragma unroll
    for (int mi = 0; mi < 4; ++mi) {
#pragma unroll
      for (int r = 0; r < 4; ++r) {
        int m = gm0 + wm + mi * 16 + q * 4 + r;
        float val = acc[mi][ni][r] + bv;
        if (out_mode == 0) {
          C[(size_t)m * N + n] = val;
        } else {
          int b = m & 31, s = m >> 5;
          C[((size_t)b * SEQ + s) * N + n] = val;
        }
      }
    }
  }
}

// ---------------- persistent LSTM: all 48 steps, custom barrier ----------------
// 256 WGs x 256 thr, 1 WG/CU (trivially co-resident: VGPR<256, LDS 8KB).
// WG g owns 4 hidden units u0=4g. Per step: 4 waves split K=1024, MFMA,
// LDS reduce, 128 activation threads update c (fp32 registers) and store h.
// Cross-XCD h exchange: writers -> relaxed AGENT atomic u32 stores
// (write-through to coherence point); readers -> sc0 sc1 asm loads.
// Barrier: monotonic counter, one relaxed agent atomicAdd per WG after
// __syncthreads() (whose vmcnt(0) drain completes the h stores), tid0
// spins on relaxed agent load + s_sleep(2). No cache maintenance at all,
// so Whh stays L1-hot and xg L2-hot across all 48 steps.
__global__ __launch_bounds__(256, 1) void lstm_persist2_kernel(
    const u16* __restrict__ Whh,      // [4096][1024] bf16
    const float* __restrict__ xg_all, // [48][32][4096] fp32
    const float* __restrict__ c_init, // [32][1024] fp32
    u16* __restrict__ Hall,           // [49][32][1024] bf16, slot 0 prefilled
    unsigned* __restrict__ bar) {     // monotonic arrive counter (pre-zeroed)
  const int u0 = blockIdx.x * 4;
  const int tid = threadIdx.x;
  const int wave = tid >> 6, lane = tid & 63;
  const int q = lane >> 4, rf = lane & 15;
  const int gate = rf >> 2, du = rf & 3;
  const int brow = gate * HID + u0 + du;

  __shared__ float red[4][32][16];   // [wave][batch][n]

  const int ab = tid >> 2, ad = tid & 3;   // activation thread: (batch, unit)
  float c_reg = 0.f;
  if (tid < 128) c_reg = c_init[ab * HID + u0 + ad];

  const u16* wp = Whh + (size_t)brow * HID + wave * 256 + q * 8;
  const unsigned nwg = gridDim.x;

  for (int s = 0; s < SEQ; ++s) {
    const u16* h_prev = Hall + (size_t)s * BATCH * HID;
    const float* xg = xg_all + (size_t)s * BATCH * 4096;
    const u16* a0p = h_prev + (size_t)rf * HID + wave * 256 + q * 8;
    const u16* a1p = a0p + 16 * HID;

    // batch-issue all 24 loads (8 W-frags cached, 16 h-frags coherent),
    // single drain, then pure-register MFMA chain.
    bf16x8 wv[8], a0v[8], a1v[8];
#pragma unroll
    for (int i = 0; i < 8; ++i) {
      ld_n16(wv[i], wp + i * 32);
      ld_c16(a0v[i], a0p + i * 32);
      ld_c16(a1v[i], a1p + i * 32);
    }
    asm volatile("s_waitcnt vmcnt(0)" ::: "memory");
    __builtin_amdgcn_sched_barrier(0);

    floatx4 acc0 = {0.f, 0.f, 0.f, 0.f}, acc1 = {0.f, 0.f, 0.f, 0.f};
#pragma unroll
    for (int i = 0; i < 8; ++i) {
      acc0 = mfma16(a0v[i], wv[i], acc0);
      acc1 = mfma16(a1v[i], wv[i], acc1);
    }

#pragma unroll
    for (int r = 0; r < 4; ++r) {
      red[wave][q * 4 + r][rf] = acc0[r];
      red[wave][16 + q * 4 + r][rf] = acc1[r];
    }
    __syncthreads();

    if (tid < 128) {
      float g4[4];
#pragma unroll
      for (int gt = 0; gt < 4; ++gt) {
        int n = gt * 4 + ad;
        float v = red[0][ab][n] + red[1][ab][n] + red[2][ab][n] + red[3][ab][n];
        v += xg[ab * 4096 + gt * HID + u0 + ad];
        g4[gt] = v;
      }
      float i_ = sigmoidf_(g4[0]);
      float f_ = sigmoidf_(g4[1]);
      float gg = tanhf(g4[2]);
      float o_ = sigmoidf_(g4[3]);
      c_reg = f_ * c_reg + i_ * gg;
      float hv = o_ * tanhf(c_reg);
      u16 hb = f2bf(hv);
      float hn = __shfl_xor(hv, 1);      // partner unit (ad^1), same wave
      u16 nb = f2bf(hn);
      if ((tid & 1) == 0) {              // ad even: pack (ad, ad+1) -> u32
        unsigned w = (unsigned)hb | ((unsigned)nb << 16);
        unsigned* dst = (unsigned*)(Hall + (size_t)(s + 1) * BATCH * HID +
                                    ab * HID + u0 + ad);
        __hip_atomic_store(dst, w, __ATOMIC_RELAXED, __HIP_MEMORY_SCOPE_AGENT);
      }
    }
    // __syncthreads drains each wave's vmcnt -> all h stores are at the
    // coherence point before this WG's arrival is visible.
    __syncthreads();
    if (tid == 0) {
      __hip_atomic_fetch_add(bar, 1u, __ATOMIC_RELAXED, __HIP_MEMORY_SCOPE_AGENT);
      unsigned target = nwg * (unsigned)(s + 1);
      while (__hip_atomic_load(bar, __ATOMIC_RELAXED, __HIP_MEMORY_SCOPE_AGENT) < target)
        __builtin_amdgcn_s_sleep(2);
    }
    __syncthreads();   // also guards red[] reuse next iteration
  }
}

extern "C" void kernel_launch(void* const* d_in, const int* in_sizes, int n_in,
                              void* d_out, int out_size, void* d_ws, size_t ws_size,
                              hipStream_t stream) {
  const int*   inputs = (const int*)d_in[0];
  const float* hidden = (const float*)d_in[1];
  const float* cell   = (const float*)d_in[2];
  const float* emb    = (const float*)d_in[3];
  const float* W_ih   = (const float*)d_in[4];
  const float* W_hh   = (const float*)d_in[5];
  const float* b_ih   = (const float*)d_in[6];
  const float* b_hh   = (const float*)d_in[7];
  const float* fc_W   = (const float*)d_in[8];
  const float* fc_b   = (const float*)d_in[9];
  float* out = (float*)d_out;

  char* ws = (char*)d_ws;
  // workspace layout (all 256B aligned), total ~108 MiB
  u16*   Xbf  = (u16*)(ws);                                  // 1536*512   bf16 = 1,572,864 B
  u16*   Wihb = (u16*)(ws + 1572864);                        // 4096*512   bf16 = 4,194,304 B
  u16*   Whhb = (u16*)(ws + 1572864 + 4194304);              // 4096*1024  bf16 = 8,388,608 B
  u16*   fcWb = (u16*)(ws + 14155776);                       // 32000*1024 bf16 = 65,536,000 B
  float* Xg   = (float*)(ws + 14155776 + 65536000);          // 1536*4096  f32  = 25,165,824 B
  u16*   Hall = (u16*)(ws + 104857600);                      // 49*32*1024 bf16 = 3,211,264 B
  unsigned* bar = (unsigned*)(ws + 104857600 + 3211264);     // barrier counter

  // 1) casts to bf16
  cast_kernel<<<(4096 * 512 / 4 + 255) / 256, 256, 0, stream>>>(W_ih, Wihb, 4096 * 512 / 4);
  cast_kernel<<<(4096 * 1024 / 4 + 255) / 256, 256, 0, stream>>>(W_hh, Whhb, 4096 * 1024 / 4);
  cast_kernel<<<(VOCAB * 1024 / 4 + 255) / 256, 256, 0, stream>>>(fc_W, fcWb, VOCAB * 1024 / 4);
  cast_kernel<<<(BATCH * HID / 4 + 255) / 256, 256, 0, stream>>>(hidden, Hall, BATCH * HID / 4); // h0 -> slot 0

  // 2) embedding gather (time-major) + barrier-counter zero
  gather_kernel<<<MROWS, 128, 0, stream>>>(inputs, emb, Xbf, bar);

  // 3) GEMM1: Xg = X @ W_ih^T + b_ih + b_hh
  gemm_bt_kernel<<<dim3(4096 / 128, MROWS / 128), 256, 0, stream>>>(
      Xbf, Wihb, b_ih, b_hh, Xg, MROWS, 4096, EMBED, 0);

  // 4) all 48 recurrent steps in ONE persistent kernel (plain launch;
  //    256 WGs x 256 thr at 1 WG/CU are co-resident by capacity)
  lstm_persist2_kernel<<<256, 256, 0, stream>>>(Whhb, Xg, cell, Hall, bar);

  // 5) GEMM2: logits = H_all[1..48] @ fc_W^T + fc_b, scattered to [B][S][V]
  gemm_bt_kernel<<<dim3(VOCAB / 128, MROWS / 128), 256, 0, stream>>>(
      Hall + (size_t)BATCH * HID, fcWb, fc_b, (const float*)nullptr, out,
      MROWS, VOCAB, HID, 1);
}

// Round 3
// 801.245 us; speedup vs baseline: 2.6306x; 1.2243x over previous
//
#include <hip/hip_runtime.h>
#include <stdint.h>

// LSTM decoder: VOCAB=32000, EMBED=512, HIDDEN=1024, B=32, S=48.
// Plan:
//   1. cast W_ih, W_hh, fc_W, hidden -> bf16 (ws)
//   2. gather X[s][b][:] = emb[inputs[b][s]] as bf16 (+ zero barrier state)
//   3. GEMM1: Xg[1536,4096] = X @ W_ih^T + b_ih + b_hh   (fp32 out)
//   4. ONE persistent kernel runs all 48 LSTM steps. Cross-XCD h exchange
//      via sc0/sc1 write-through stores + sc0/sc1 loads (L3 = coherence
//      point). Barrier: hierarchical monotonic counters (8 group lines ->
//      1 root) with a SEPARATE release line for polling, so arrival
//      atomics never contend with spin loads (round-2 hot-line fix).
//   5. GEMM2: out[b][s][v] = H_all[1..48] @ fc_W^T + fc_b (fp32, scatter)
// GEMM block mapping: identity (the round-1/2 m-fastest XCD remap thrashed
// L2 A-reuse and cost ~250us on GEMM2 — reverted).

typedef unsigned short u16;
typedef __attribute__((ext_vector_type(8))) short bf16x8;
typedef __attribute__((ext_vector_type(4))) float floatx4;
struct alignas(8) us4 { u16 x, y, z, w; };

#define BATCH 32
#define SEQ   48
#define EMBED 512
#define HID   1024
#define VOCAB 32000
#define MROWS (SEQ * BATCH)   // 1536

__device__ __forceinline__ u16 f2bf(float f) {
  unsigned u = __float_as_uint(f);
  u += 0x7FFF + ((u >> 16) & 1);   // round-to-nearest-even
  return (u16)(u >> 16);
}

__device__ __forceinline__ floatx4 mfma16(bf16x8 a, bf16x8 b, floatx4 c) {
  return __builtin_amdgcn_mfma_f32_16x16x32_bf16(a, b, c, 0, 0, 0);
}

// async global->LDS, 16B per lane; lds base must be wave-uniform
typedef __attribute__((address_space(1))) unsigned int as1_uint;
typedef __attribute__((address_space(3))) unsigned int as3_uint;
__device__ __forceinline__ void gl_lds16(const void* g, void* l) {
  __builtin_amdgcn_global_load_lds((as1_uint*)g, (as3_uint*)l, 16, 0, 0);
}

__device__ __forceinline__ float sigmoidf_(float x) {
  return 1.0f / (1.0f + __expf(-x));
}

// coherent 16B load: bypass L1/L2, read at coherence point (L3).
// No waitcnt inside — caller batches issues then drains once, followed by
// sched_barrier(0) so MFMA can't be hoisted above the drain (rule #18).
__device__ __forceinline__ void ld_c16(bf16x8& d, const u16* p) {
  asm volatile("global_load_dwordx4 %0, %1, off sc0 sc1" : "=&v"(d) : "v"(p));
}
// plain cached 16B load, same batched-issue pattern
__device__ __forceinline__ void ld_n16(bf16x8& d, const u16* p) {
  asm volatile("global_load_dwordx4 %0, %1, off" : "=&v"(d) : "v"(p));
}

// barrier state layout (u32 indices within bar):
//   grp g   : bar[g*64]      g=0..7   (256B-spaced lines)
//   root    : bar[512]
//   release : bar[544]                (own line, polled)
#define BAR_U32S 576

// ---------------- cast fp32 -> bf16, 4 elems/thread, n % 4 == 0 ----------------
__global__ void cast_kernel(const float* __restrict__ in, u16* __restrict__ out, int n4) {
  int i = blockIdx.x * blockDim.x + threadIdx.x;
  if (i < n4) {
    float4 v = *(const float4*)(in + (size_t)i * 4);
    us4 o;
    o.x = f2bf(v.x); o.y = f2bf(v.y); o.z = f2bf(v.z); o.w = f2bf(v.w);
    *(us4*)(out + (size_t)i * 4) = o;
  }
}

// ---------------- embedding gather: X[s*32+b][:] = bf16(emb[idx[b][s]]) --------
// block 0 also zeroes the persistent-LSTM barrier state (graph replays reuse ws)
__global__ void gather_kernel(const int* __restrict__ idx, const float* __restrict__ emb,
                              u16* __restrict__ X, unsigned* __restrict__ bar) {
  int bid = blockIdx.x;          // = s*32 + b
  if (bid == 0) {
    for (int j = threadIdx.x; j < BAR_U32S; j += 128) bar[j] = 0u;
  }
  int s = bid >> 5, b = bid & 31;
  int t = idx[b * SEQ + s];
  const float* src = emb + (size_t)t * EMBED;
  u16* dst = X + (size_t)bid * EMBED;
  int e = threadIdx.x * 4;       // 128 threads * 4 = 512
  float4 v = *(const float4*)(src + e);
  us4 o;
  o.x = f2bf(v.x); o.y = f2bf(v.y); o.z = f2bf(v.z); o.w = f2bf(v.w);
  *(us4*)(dst + e) = o;
}

// ---------------- tiled bf16 GEMM: C = A[M,K] @ B[N,K]^T + bias ----------------
// 128x128 tile, BK=64, 4 waves, each wave 64x64 via 4x4 16x16x32 MFMA tiles.
// LDS chunks (16B) XOR-swizzled by row to avoid ds_read_b128 bank conflicts;
// swizzle is applied to the per-lane GLOBAL address so global_load_lds's
// wave-uniform-base + lane*16 LDS destination stays contiguous.
// out_mode 0: C[m*N + n]   (row-major)
// out_mode 1: C[(b*SEQ + s)*N + n] with b=m&31, s=m>>5  (logits scatter)
__global__ __launch_bounds__(256) void gemm_bt_kernel(
    const u16* __restrict__ A, const u16* __restrict__ B,
    const float* __restrict__ bias0, const float* __restrict__ bias1,
    float* __restrict__ C, int M, int N, int K, int out_mode) {
  __shared__ u16 As[128 * 64];   // row r: 8 chunks of 8 bf16; chunk p holds global chunk p^(r&7)
  __shared__ u16 Bs[128 * 64];

  const int tid = threadIdx.x;
  const int wave = tid >> 6, lane = tid & 63;
  const int l3 = lane >> 3, l7 = lane & 7;
  const int q = lane >> 4, rf = lane & 15;
  const int tn = blockIdx.x, tm = blockIdx.y;
  const int gm0 = tm * 128, gn0 = tn * 128;
  const int wm = (wave & 1) * 64, wn = (wave >> 1) * 64;

  floatx4 acc[4][4];
#pragma unroll
  for (int i = 0; i < 4; ++i)
#pragma unroll
    for (int j = 0; j < 4; ++j) acc[i][j] = (floatx4){0.f, 0.f, 0.f, 0.f};

  for (int k0 = 0; k0 < K; k0 += 64) {
    // stage: 16 wave-issues each cover 8 rows x 8 chunks (1 KiB LDS)
#pragma unroll
    for (int i = 0; i < 4; ++i) {
      int e = wave * 4 + i;
      int r = e * 8 + l3;
      int qd = l7 ^ (r & 7);
      gl_lds16(A + (size_t)(gm0 + r) * K + k0 + qd * 8, (void*)(As + e * 512));
      gl_lds16(B + (size_t)(gn0 + r) * K + k0 + qd * 8, (void*)(Bs + e * 512));
    }
    __syncthreads();   // compiler emits vmcnt(0) drain before barrier

#pragma unroll
    for (int kk = 0; kk < 64; kk += 32) {
      int jc = (kk >> 3) + q;   // global 16B chunk index for this quad
      bf16x8 af[4], bf[4];
#pragma unroll
      for (int mi = 0; mi < 4; ++mi) {
        int r = wm + mi * 16 + rf;
        af[mi] = *(const bf16x8*)(As + r * 64 + (jc ^ (r & 7)) * 8);
      }
#pragma unroll
      for (int ni = 0; ni < 4; ++ni) {
        int r = wn + ni * 16 + rf;
        bf[ni] = *(const bf16x8*)(Bs + r * 64 + (jc ^ (r & 7)) * 8);
      }
#pragma unroll
      for (int mi = 0; mi < 4; ++mi)
#pragma unroll
        for (int ni = 0; ni < 4; ++ni)
          acc[mi][ni] = mfma16(af[mi], bf[ni], acc[mi][ni]);
    }
    __syncthreads();
  }

  // epilogue: D row = q*4 + reg (m), col = lane&15 (n)
#pragma unroll
  for (int ni = 0; ni < 4; ++ni) {
    int n = gn0 + wn + ni * 16 + rf;
    float bv = bias0[n];
    if (bias1) bv += bias1[n];
#pragma unroll
    for (int mi = 0; mi < 4; ++mi) {
#pragma unroll
      for (int r = 0; r < 4; ++r) {
        int m = gm0 + wm + mi * 16 + q * 4 + r;
        float val = acc[mi][ni][r] + bv;
        if (out_mode == 0) {
          C[(size_t)m * N + n] = val;
        } else {
          int b = m & 31, s = m >> 5;
          C[((size_t)b * SEQ + s) * N + n] = val;
        }
      }
    }
  }
}

// ---------------- persistent LSTM: all 48 steps, hierarchical barrier ----------
// 256 WGs x 256 thr, 1 WG/CU. WG g owns 4 hidden units u0=4g. Per step:
// 4 waves split K=1024 (MFMA on 24 batched loads), LDS reduce, 128
// activation threads update c (fp32 registers) and store h (packed u32
// sc0/sc1 write-through). Barrier: tid0 atomicAdd -> grp line (32 arrivals,
// 8 parallel lines), group-last bumps root (8 arrivals), overall-last
// stores s+1 to the release line; everyone polls release only.
__global__ __launch_bounds__(256, 1) void lstm_persist3_kernel(
    const u16* __restrict__ Whh,      // [4096][1024] bf16
    const float* __restrict__ xg_all, // [48][32][4096] fp32
    const float* __restrict__ c_init, // [32][1024] fp32
    u16* __restrict__ Hall,           // [49][32][1024] bf16, slot 0 prefilled
    unsigned* __restrict__ bar) {     // barrier state (pre-zeroed)
  const int bid = blockIdx.x;
  const int u0 = bid * 4;
  const int tid = threadIdx.x;
  const int wave = tid >> 6, lane = tid & 63;
  const int q = lane >> 4, rf = lane & 15;
  const int gate = rf >> 2, du = rf & 3;
  const int brow = gate * HID + u0 + du;

  __shared__ float red[4][32][16];   // [wave][batch][n]

  const int ab = tid >> 2, ad = tid & 3;   // activation thread: (batch, unit)
  float c_reg = 0.f;
  if (tid < 128) c_reg = c_init[ab * HID + u0 + ad];

  const u16* wp = Whh + (size_t)brow * HID + wave * 256 + q * 8;
  unsigned* gcnt   = bar + (bid & 7) * 64;
  unsigned* root    = bar + 512;
  unsigned* release = bar + 544;

  for (int s = 0; s < SEQ; ++s) {
    const u16* h_prev = Hall + (size_t)s * BATCH * HID;
    const float* xg = xg_all + (size_t)s * BATCH * 4096;
    const u16* a0p = h_prev + (size_t)rf * HID + wave * 256 + q * 8;
    const u16* a1p = a0p + 16 * HID;

    // hoist xg loads (L2-resident) so they drain with the h/W fragments
    float xgv[4];
    if (tid < 128) {
#pragma unroll
      for (int gt = 0; gt < 4; ++gt) xgv[gt] = xg[ab * 4096 + gt * HID + u0 + ad];
    }

    // batch-issue all 24 loads (8 W-frags cached, 16 h-frags coherent),
    // single drain, then pure-register MFMA chain.
    bf16x8 wv[8], a0v[8], a1v[8];
#pragma unroll
    for (int i = 0; i < 8; ++i) {
      ld_n16(wv[i], wp + i * 32);
      ld_c16(a0v[i], a0p + i * 32);
      ld_c16(a1v[i], a1p + i * 32);
    }
    asm volatile("s_waitcnt vmcnt(0)" ::: "memory");
    __builtin_amdgcn_sched_barrier(0);

    floatx4 acc0 = {0.f, 0.f, 0.f, 0.f}, acc1 = {0.f, 0.f, 0.f, 0.f};
#pragma unroll
    for (int i = 0; i < 8; ++i) {
      acc0 = mfma16(a0v[i], wv[i], acc0);
      acc1 = mfma16(a1v[i], wv[i], acc1);
    }

#pragma unroll
    for (int r = 0; r < 4; ++r) {
      red[wave][q * 4 + r][rf] = acc0[r];
      red[wave][16 + q * 4 + r][rf] = acc1[r];
    }
    __syncthreads();

    if (tid < 128) {
      float g4[4];
#pragma unroll
      for (int gt = 0; gt < 4; ++gt) {
        int n = gt * 4 + ad;
        float v = red[0][ab][n] + red[1][ab][n] + red[2][ab][n] + red[3][ab][n];
        g4[gt] = v + xgv[gt];
      }
      float i_ = sigmoidf_(g4[0]);
      float f_ = sigmoidf_(g4[1]);
      float gg = tanhf(g4[2]);
      float o_ = sigmoidf_(g4[3]);
      c_reg = f_ * c_reg + i_ * gg;
      float hv = o_ * tanhf(c_reg);
      u16 hb = f2bf(hv);
      float hn = __shfl_xor(hv, 1);      // partner unit (ad^1), same wave
      u16 nb = f2bf(hn);
      if ((tid & 1) == 0) {              // ad even: pack (ad, ad+1) -> u32
        unsigned w = (unsigned)hb | ((unsigned)nb << 16);
        unsigned* dst = (unsigned*)(Hall + (size_t)(s + 1) * BATCH * HID +
                                    ab * HID + u0 + ad);
        __hip_atomic_store(dst, w, __ATOMIC_RELAXED, __HIP_MEMORY_SCOPE_AGENT);
      }
    }
    // __syncthreads drains each wave's vmcnt -> all h stores are at the
    // coherence point before this WG's arrival is visible.
    __syncthreads();
    if (tid == 0) {
      unsigned old = __hip_atomic_fetch_add(gcnt, 1u, __ATOMIC_RELAXED,
                                            __HIP_MEMORY_SCOPE_AGENT);
      if (old + 1 == 32u * (unsigned)(s + 1)) {      // last in group
        unsigned r = __hip_atomic_fetch_add(root, 1u, __ATOMIC_RELAXED,
                                            __HIP_MEMORY_SCOPE_AGENT);
        if (r + 1 == 8u * (unsigned)(s + 1)) {       // last overall
          __hip_atomic_store(release, (unsigned)(s + 1), __ATOMIC_RELAXED,
                             __HIP_MEMORY_SCOPE_AGENT);
        }
      }
      while (__hip_atomic_load(release, __ATOMIC_RELAXED,
                               __HIP_MEMORY_SCOPE_AGENT) < (unsigned)(s + 1))
        __builtin_amdgcn_s_sleep(2);
    }
    __syncthreads();   // also guards red[] reuse next iteration
  }
}

extern "C" void kernel_launch(void* const* d_in, const int* in_sizes, int n_in,
                              void* d_out, int out_size, void* d_ws, size_t ws_size,
                              hipStream_t stream) {
  const int*   inputs = (const int*)d_in[0];
  const float* hidden = (const float*)d_in[1];
  const float* cell   = (const float*)d_in[2];
  const float* emb    = (const float*)d_in[3];
  const float* W_ih   = (const float*)d_in[4];
  const float* W_hh   = (const float*)d_in[5];
  const float* b_ih   = (const float*)d_in[6];
  const float* b_hh   = (const float*)d_in[7];
  const float* fc_W   = (const float*)d_in[8];
  const float* fc_b   = (const float*)d_in[9];
  float* out = (float*)d_out;

  char* ws = (char*)d_ws;
  // workspace layout (all 256B aligned), total ~108 MiB
  u16*   Xbf  = (u16*)(ws);                                  // 1536*512   bf16 = 1,572,864 B
  u16*   Wihb = (u16*)(ws + 1572864);                        // 4096*512   bf16 = 4,194,304 B
  u16*   Whhb = (u16*)(ws + 1572864 + 4194304);              // 4096*1024  bf16 = 8,388,608 B
  u16*   fcWb = (u16*)(ws + 14155776);                       // 32000*1024 bf16 = 65,536,000 B
  float* Xg   = (float*)(ws + 14155776 + 65536000);          // 1536*4096  f32  = 25,165,824 B
  u16*   Hall = (u16*)(ws + 104857600);                      // 49*32*1024 bf16 = 3,211,264 B
  unsigned* bar = (unsigned*)(ws + 104857600 + 3211264);     // barrier state

  // 1) casts to bf16
  cast_kernel<<<(4096 * 512 / 4 + 255) / 256, 256, 0, stream>>>(W_ih, Wihb, 4096 * 512 / 4);
  cast_kernel<<<(4096 * 1024 / 4 + 255) / 256, 256, 0, stream>>>(W_hh, Whhb, 4096 * 1024 / 4);
  cast_kernel<<<(VOCAB * 1024 / 4 + 255) / 256, 256, 0, stream>>>(fc_W, fcWb, VOCAB * 1024 / 4);
  cast_kernel<<<(BATCH * HID / 4 + 255) / 256, 256, 0, stream>>>(hidden, Hall, BATCH * HID / 4); // h0 -> slot 0

  // 2) embedding gather (time-major) + barrier-state zero
  gather_kernel<<<MROWS, 128, 0, stream>>>(inputs, emb, Xbf, bar);

  // 3) GEMM1: Xg = X @ W_ih^T + b_ih + b_hh
  gemm_bt_kernel<<<dim3(4096 / 128, MROWS / 128), 256, 0, stream>>>(
      Xbf, Wihb, b_ih, b_hh, Xg, MROWS, 4096, EMBED, 0);

  // 4) all 48 recurrent steps in ONE persistent kernel (plain launch;
  //    256 WGs x 256 thr at 1 WG/CU are co-resident by capacity)
  lstm_persist3_kernel<<<256, 256, 0, stream>>>(Whhb, Xg, cell, Hall, bar);

  // 5) GEMM2: logits = H_all[1..48] @ fc_W^T + fc_b, scattered to [B][S][V]
  gemm_bt_kernel<<<dim3(VOCAB / 128, MROWS / 128), 256, 0, stream>>>(
      Hall + (size_t)BATCH * HID, fcWb, fc_b, (const float*)nullptr, out,
      MROWS, VOCAB, HID, 1);
}

// Round 4
// 723.825 us; speedup vs baseline: 2.9120x; 1.1070x over previous
//
#include <hip/hip_runtime.h>
#include <stdint.h>

// LSTM decoder: VOCAB=32000, EMBED=512, HIDDEN=1024, B=32, S=48.
// Plan:
//   1. one fused cast kernel: W_ih, W_hh, fc_W, hidden -> bf16 (ws)
//   2. gather X[s][b][:] = emb[inputs[b][s]] as bf16 (+ zero barrier state)
//   3. GEMM1: Xg[1536,4096] = X @ W_ih^T + b_ih + b_hh   (fp32 out, 128-tile)
//   4. ONE persistent kernel runs all 48 LSTM steps. Per-step critical path
//      minimized: W_hh fragments live in VGPRs for the whole kernel (zero
//      loads/step), xg prefetched during the previous barrier wait, so only
//      the 16 h-fragment loads (sc0/sc1, L3) sit behind the release.
//      Barrier: hierarchical counters (8 group lines -> root -> release
//      line, polled only); final step skips the barrier entirely.
//   5. GEMM2: 256x128-tile GEMM (8 waves) halves fc_W L2 refetch
//      (12 -> 6 m-tiles); logits scattered to [B][S][V].

typedef unsigned short u16;
typedef __attribute__((ext_vector_type(8))) short bf16x8;
typedef __attribute__((ext_vector_type(4))) float floatx4;
struct alignas(8) us4 { u16 x, y, z, w; };

#define BATCH 32
#define SEQ   48
#define EMBED 512
#define HID   1024
#define VOCAB 32000
#define MROWS (SEQ * BATCH)   // 1536

__device__ __forceinline__ u16 f2bf(float f) {
  unsigned u = __float_as_uint(f);
  u += 0x7FFF + ((u >> 16) & 1);   // round-to-nearest-even
  return (u16)(u >> 16);
}

__device__ __forceinline__ floatx4 mfma16(bf16x8 a, bf16x8 b, floatx4 c) {
  return __builtin_amdgcn_mfma_f32_16x16x32_bf16(a, b, c, 0, 0, 0);
}

// async global->LDS, 16B per lane; lds base must be wave-uniform
typedef __attribute__((address_space(1))) unsigned int as1_uint;
typedef __attribute__((address_space(3))) unsigned int as3_uint;
__device__ __forceinline__ void gl_lds16(const void* g, void* l) {
  __builtin_amdgcn_global_load_lds((as1_uint*)g, (as3_uint*)l, 16, 0, 0);
}

__device__ __forceinline__ float sigmoidf_(float x) {
  return 1.0f / (1.0f + __expf(-x));
}

// coherent 16B load: bypass L1/L2, read at coherence point (L3).
// No waitcnt inside — caller batches issues then drains once, followed by
// sched_barrier(0) so MFMA can't be hoisted above the drain (rule #18).
__device__ __forceinline__ void ld_c16(bf16x8& d, const u16* p) {
  asm volatile("global_load_dwordx4 %0, %1, off sc0 sc1" : "=&v"(d) : "v"(p));
}
// plain cached 16B load, same batched-issue pattern
__device__ __forceinline__ void ld_n16(bf16x8& d, const u16* p) {
  asm volatile("global_load_dwordx4 %0, %1, off" : "=&v"(d) : "v"(p));
}

// barrier state layout (u32 indices within bar):
//   grp g   : bar[g*64]      g=0..7   (256B-spaced lines)
//   root    : bar[512]
//   release : bar[544]                (own line, polled)
#define BAR_U32S 576

// ---------------- fused cast fp32 -> bf16 for all 4 tensors --------------------
__global__ void cast_all_kernel(const float* __restrict__ s0, u16* __restrict__ d0, int n0,
                                const float* __restrict__ s1, u16* __restrict__ d1, int n1,
                                const float* __restrict__ s2, u16* __restrict__ d2, int n2,
                                const float* __restrict__ s3, u16* __restrict__ d3, int n3) {
  int i = blockIdx.x * blockDim.x + threadIdx.x;   // one float4 per thread
  const float* src; u16* dst; int off;
  if (i < n0)                     { src = s0; dst = d0; off = i; }
  else if (i < n0 + n1)           { src = s1; dst = d1; off = i - n0; }
  else if (i < n0 + n1 + n2)      { src = s2; dst = d2; off = i - n0 - n1; }
  else if (i < n0 + n1 + n2 + n3) { src = s3; dst = d3; off = i - n0 - n1 - n2; }
  else return;
  float4 v = *(const float4*)(src + (size_t)off * 4);
  us4 o;
  o.x = f2bf(v.x); o.y = f2bf(v.y); o.z = f2bf(v.z); o.w = f2bf(v.w);
  *(us4*)(dst + (size_t)off * 4) = o;
}

// ---------------- embedding gather: X[s*32+b][:] = bf16(emb[idx[b][s]]) --------
// block 0 also zeroes the persistent-LSTM barrier state (graph replays reuse ws)
__global__ void gather_kernel(const int* __restrict__ idx, const float* __restrict__ emb,
                              u16* __restrict__ X, unsigned* __restrict__ bar) {
  int bid = blockIdx.x;          // = s*32 + b
  if (bid == 0) {
    for (int j = threadIdx.x; j < BAR_U32S; j += 128) bar[j] = 0u;
  }
  int s = bid >> 5, b = bid & 31;
  int t = idx[b * SEQ + s];
  const float* src = emb + (size_t)t * EMBED;
  u16* dst = X + (size_t)bid * EMBED;
  int e = threadIdx.x * 4;       // 128 threads * 4 = 512
  float4 v = *(const float4*)(src + e);
  us4 o;
  o.x = f2bf(v.x); o.y = f2bf(v.y); o.z = f2bf(v.z); o.w = f2bf(v.w);
  *(us4*)(dst + e) = o;
}

// ---------------- tiled bf16 GEMM (128x128): C = A @ B^T + bias ----------------
// used for GEMM1 (row-major out). 4 waves, BK=64, XOR-swizzled LDS chunks.
__global__ __launch_bounds__(256) void gemm_bt_kernel(
    const u16* __restrict__ A, const u16* __restrict__ B,
    const float* __restrict__ bias0, const float* __restrict__ bias1,
    float* __restrict__ C, int M, int N, int K) {
  __shared__ u16 As[128 * 64];   // row r: 8 chunks of 8 bf16; chunk p holds global chunk p^(r&7)
  __shared__ u16 Bs[128 * 64];

  const int tid = threadIdx.x;
  const int wave = tid >> 6, lane = tid & 63;
  const int l3 = lane >> 3, l7 = lane & 7;
  const int q = lane >> 4, rf = lane & 15;
  const int tn = blockIdx.x, tm = blockIdx.y;
  const int gm0 = tm * 128, gn0 = tn * 128;
  const int wm = (wave & 1) * 64, wn = (wave >> 1) * 64;

  floatx4 acc[4][4];
#pragma unroll
  for (int i = 0; i < 4; ++i)
#pragma unroll
    for (int j = 0; j < 4; ++j) acc[i][j] = (floatx4){0.f, 0.f, 0.f, 0.f};

  for (int k0 = 0; k0 < K; k0 += 64) {
#pragma unroll
    for (int i = 0; i < 4; ++i) {
      int e = wave * 4 + i;
      int r = e * 8 + l3;
      int qd = l7 ^ (r & 7);
      gl_lds16(A + (size_t)(gm0 + r) * K + k0 + qd * 8, (void*)(As + e * 512));
      gl_lds16(B + (size_t)(gn0 + r) * K + k0 + qd * 8, (void*)(Bs + e * 512));
    }
    __syncthreads();

#pragma unroll
    for (int kk = 0; kk < 64; kk += 32) {
      int jc = (kk >> 3) + q;
      bf16x8 af[4], bf[4];
#pragma unroll
      for (int mi = 0; mi < 4; ++mi) {
        int r = wm + mi * 16 + rf;
        af[mi] = *(const bf16x8*)(As + r * 64 + (jc ^ (r & 7)) * 8);
      }
#pragma unroll
      for (int ni = 0; ni < 4; ++ni) {
        int r = wn + ni * 16 + rf;
        bf[ni] = *(const bf16x8*)(Bs + r * 64 + (jc ^ (r & 7)) * 8);
      }
#pragma unroll
      for (int mi = 0; mi < 4; ++mi)
#pragma unroll
        for (int ni = 0; ni < 4; ++ni)
          acc[mi][ni] = mfma16(af[mi], bf[ni], acc[mi][ni]);
    }
    __syncthreads();
  }

#pragma unroll
  for (int ni = 0; ni < 4; ++ni) {
    int n = gn0 + wn + ni * 16 + rf;
    float bv = bias0[n];
    if (bias1) bv += bias1[n];
#pragma unroll
    for (int mi = 0; mi < 4; ++mi) {
#pragma unroll
      for (int r = 0; r < 4; ++r) {
        int m = gm0 + wm + mi * 16 + q * 4 + r;
        C[(size_t)m * N + n] = acc[mi][ni][r] + bv;
      }
    }
  }
}

// ---------------- tiled bf16 GEMM (256x128, 8 waves): logits + scatter ---------
// 256-row m-tile halves the fc_W (B) L2 refetch: 6 m-tiles instead of 12.
// LDS 48 KB (As 32K + Bs 16K), 8 waves in 4m x 2n grid, each 64x64.
// out: C[(b*SEQ + s)*N + n] with b=m&31, s=m>>5  (logits scatter)
__global__ __launch_bounds__(512) void gemm_bt256_kernel(
    const u16* __restrict__ A, const u16* __restrict__ B,
    const float* __restrict__ bias0, float* __restrict__ C,
    int N, int K) {
  __shared__ u16 As[256 * 64];   // 32 KB
  __shared__ u16 Bs[128 * 64];   // 16 KB

  const int tid = threadIdx.x;
  const int wave = tid >> 6, lane = tid & 63;   // 8 waves
  const int l3 = lane >> 3, l7 = lane & 7;
  const int q = lane >> 4, rf = lane & 15;
  const int tn = blockIdx.x, tm = blockIdx.y;
  const int gm0 = tm * 256, gn0 = tn * 128;
  const int wm = (wave & 3) * 64, wn = (wave >> 2) * 64;

  floatx4 acc[4][4];
#pragma unroll
  for (int i = 0; i < 4; ++i)
#pragma unroll
    for (int j = 0; j < 4; ++j) acc[i][j] = (floatx4){0.f, 0.f, 0.f, 0.f};

  for (int k0 = 0; k0 < K; k0 += 64) {
    // stage 48 wave-issues: e<32 -> As rows e*8.., else Bs rows (e-32)*8..
#pragma unroll
    for (int i = 0; i < 6; ++i) {
      int e = wave * 6 + i;
      if (e < 32) {
        int r = e * 8 + l3;
        int qd = l7 ^ (r & 7);
        gl_lds16(A + (size_t)(gm0 + r) * K + k0 + qd * 8, (void*)(As + e * 512));
      } else {
        int e2 = e - 32;
        int r = e2 * 8 + l3;
        int qd = l7 ^ (r & 7);
        gl_lds16(B + (size_t)(gn0 + r) * K + k0 + qd * 8, (void*)(Bs + e2 * 512));
      }
    }
    __syncthreads();

#pragma unroll
    for (int kk = 0; kk < 64; kk += 32) {
      int jc = (kk >> 3) + q;
      bf16x8 af[4], bf[4];
#pragma unroll
      for (int mi = 0; mi < 4; ++mi) {
        int r = wm + mi * 16 + rf;
        af[mi] = *(const bf16x8*)(As + r * 64 + (jc ^ (r & 7)) * 8);
      }
#pragma unroll
      for (int ni = 0; ni < 4; ++ni) {
        int r = wn + ni * 16 + rf;
        bf[ni] = *(const bf16x8*)(Bs + r * 64 + (jc ^ (r & 7)) * 8);
      }
#pragma unroll
      for (int mi = 0; mi < 4; ++mi)
#pragma unroll
        for (int ni = 0; ni < 4; ++ni)
          acc[mi][ni] = mfma16(af[mi], bf[ni], acc[mi][ni]);
    }
    __syncthreads();
  }

#pragma unroll
  for (int ni = 0; ni < 4; ++ni) {
    int n = gn0 + wn + ni * 16 + rf;
    float bv = bias0[n];
#pragma unroll
    for (int mi = 0; mi < 4; ++mi) {
#pragma unroll
      for (int r = 0; r < 4; ++r) {
        int m = gm0 + wm + mi * 16 + q * 4 + r;
        int b = m & 31, s = m >> 5;
        C[((size_t)b * SEQ + s) * N + n] = acc[mi][ni][r] + bv;
      }
    }
  }
}

// ---------------- persistent LSTM: all 48 steps, minimized critical path -------
// 256 WGs x 256 thr, 1 WG/CU. WG g owns 4 hidden units u0=4g.
// W_hh fragments: loaded ONCE into 32 VGPRs, reused all 48 steps.
// xg: prefetched for step s+1 during the barrier wait of step s.
// Post-release path per step: 16 h-loads (sc0/sc1) -> drain -> 16 MFMA ->
// LDS reduce -> activation (c in fp32 regs) -> packed sc0/sc1 h store ->
// drain -> hierarchical arrive. Step 47 skips the barrier (kernel-end
// ordering covers GEMM2's reads).
__global__ __launch_bounds__(256, 1) void lstm_persist4_kernel(
    const u16* __restrict__ Whh,      // [4096][1024] bf16
    const float* __restrict__ xg_all, // [48][32][4096] fp32
    const float* __restrict__ c_init, // [32][1024] fp32
    u16* __restrict__ Hall,           // [49][32][1024] bf16, slot 0 prefilled
    unsigned* __restrict__ bar) {     // barrier state (pre-zeroed)
  const int bid = blockIdx.x;
  const int u0 = bid * 4;
  const int tid = threadIdx.x;
  const int wave = tid >> 6, lane = tid & 63;
  const int q = lane >> 4, rf = lane & 15;
  const int gate = rf >> 2, du = rf & 3;
  const int brow = gate * HID + u0 + du;

  __shared__ float red[4][32][16];   // [wave][batch][n]

  const int ab = tid >> 2, ad = tid & 3;   // activation thread: (batch, unit)
  float c_reg = 0.f;
  if (tid < 128) c_reg = c_init[ab * HID + u0 + ad];

  // W_hh fragments resident in registers for the whole kernel (32 VGPRs)
  const u16* wp = Whh + (size_t)brow * HID + wave * 256 + q * 8;
  bf16x8 wv[8];
#pragma unroll
  for (int i = 0; i < 8; ++i) ld_n16(wv[i], wp + i * 32);
  // (drained by the first per-step vmcnt(0) below)

  // prefetch xg for step 0
  float xgv[4];
  if (tid < 128) {
#pragma unroll
    for (int gt = 0; gt < 4; ++gt) xgv[gt] = xg_all[ab * 4096 + gt * HID + u0 + ad];
  }

  unsigned* gcnt    = bar + (bid & 7) * 64;
  unsigned* root    = bar + 512;
  unsigned* release = bar + 544;

  for (int s = 0; s < SEQ; ++s) {
    // wait until h_s is published (release == s); s=0 ready via stream order
    if (s > 0) {
      if (tid == 0) {
        while (__hip_atomic_load(release, __ATOMIC_RELAXED,
                                 __HIP_MEMORY_SCOPE_AGENT) < (unsigned)s)
          __builtin_amdgcn_s_sleep(2);
      }
      __syncthreads();
    }

    // only the h loads sit on the post-release critical path
    const u16* a0p = Hall + (size_t)s * BATCH * HID + (size_t)rf * HID + wave * 256 + q * 8;
    const u16* a1p = a0p + 16 * HID;
    bf16x8 a0v[8], a1v[8];
#pragma unroll
    for (int i = 0; i < 8; ++i) {
      ld_c16(a0v[i], a0p + i * 32);
      ld_c16(a1v[i], a1p + i * 32);
    }
    asm volatile("s_waitcnt vmcnt(0)" ::: "memory");
    __builtin_amdgcn_sched_barrier(0);

    floatx4 acc0 = {0.f, 0.f, 0.f, 0.f}, acc1 = {0.f, 0.f, 0.f, 0.f};
#pragma unroll
    for (int i = 0; i < 8; ++i) {
      acc0 = mfma16(a0v[i], wv[i], acc0);
      acc1 = mfma16(a1v[i], wv[i], acc1);
    }

#pragma unroll
    for (int r = 0; r < 4; ++r) {
      red[wave][q * 4 + r][rf] = acc0[r];
      red[wave][16 + q * 4 + r][rf] = acc1[r];
    }
    __syncthreads();

    if (tid < 128) {
      float g4[4];
#pragma unroll
      for (int gt = 0; gt < 4; ++gt) {
        int n = gt * 4 + ad;
        float v = red[0][ab][n] + red[1][ab][n] + red[2][ab][n] + red[3][ab][n];
        g4[gt] = v + xgv[gt];
      }
      float i_ = sigmoidf_(g4[0]);
      float f_ = sigmoidf_(g4[1]);
      float gg = tanhf(g4[2]);
      float o_ = sigmoidf_(g4[3]);
      c_reg = f_ * c_reg + i_ * gg;
      float hv = o_ * tanhf(c_reg);
      u16 hb = f2bf(hv);
      float hn = __shfl_xor(hv, 1);      // partner unit (ad^1), same wave
      u16 nb = f2bf(hn);
      if ((tid & 1) == 0) {              // ad even: pack (ad, ad+1) -> u32
        unsigned w = (unsigned)hb | ((unsigned)nb << 16);
        unsigned* dst = (unsigned*)(Hall + (size_t)(s + 1) * BATCH * HID +
                                    ab * HID + u0 + ad);
        __hip_atomic_store(dst, w, __ATOMIC_RELAXED, __HIP_MEMORY_SCOPE_AGENT);
      }
    }
    // __syncthreads drains each wave's vmcnt -> h stores are at the
    // coherence point before this WG's arrival is visible.
    __syncthreads();

    if (s < SEQ - 1) {
      if (tid == 0) {
        unsigned old = __hip_atomic_fetch_add(gcnt, 1u, __ATOMIC_RELAXED,
                                              __HIP_MEMORY_SCOPE_AGENT);
        if (old + 1 == 32u * (unsigned)(s + 1)) {      // last in group
          unsigned r = __hip_atomic_fetch_add(root, 1u, __ATOMIC_RELAXED,
                                              __HIP_MEMORY_SCOPE_AGENT);
          if (r + 1 == 8u * (unsigned)(s + 1)) {       // last overall
            __hip_atomic_store(release, (unsigned)(s + 1), __ATOMIC_RELAXED,
                               __HIP_MEMORY_SCOPE_AGENT);
          }
        }
      }
      // prefetch xg for s+1 — overlaps the barrier wait at the next loop top
      if (tid < 128) {
        const float* xgn = xg_all + (size_t)(s + 1) * BATCH * 4096;
#pragma unroll
        for (int gt = 0; gt < 4; ++gt) xgv[gt] = xgn[ab * 4096 + gt * HID + u0 + ad];
      }
    }
  }
}

extern "C" void kernel_launch(void* const* d_in, const int* in_sizes, int n_in,
                              void* d_out, int out_size, void* d_ws, size_t ws_size,
                              hipStream_t stream) {
  const int*   inputs = (const int*)d_in[0];
  const float* hidden = (const float*)d_in[1];
  const float* cell   = (const float*)d_in[2];
  const float* emb    = (const float*)d_in[3];
  const float* W_ih   = (const float*)d_in[4];
  const float* W_hh   = (const float*)d_in[5];
  const float* b_ih   = (const float*)d_in[6];
  const float* b_hh   = (const float*)d_in[7];
  const float* fc_W   = (const float*)d_in[8];
  const float* fc_b   = (const float*)d_in[9];
  float* out = (float*)d_out;

  char* ws = (char*)d_ws;
  // workspace layout (all 256B aligned), total ~108 MiB
  u16*   Xbf  = (u16*)(ws);                                  // 1536*512   bf16 = 1,572,864 B
  u16*   Wihb = (u16*)(ws + 1572864);                        // 4096*512   bf16 = 4,194,304 B
  u16*   Whhb = (u16*)(ws + 1572864 + 4194304);              // 4096*1024  bf16 = 8,388,608 B
  u16*   fcWb = (u16*)(ws + 14155776);                       // 32000*1024 bf16 = 65,536,000 B
  float* Xg   = (float*)(ws + 14155776 + 65536000);          // 1536*4096  f32  = 25,165,824 B
  u16*   Hall = (u16*)(ws + 104857600);                      // 49*32*1024 bf16 = 3,211,264 B
  unsigned* bar = (unsigned*)(ws + 104857600 + 3211264);     // barrier state

  // 1) fused casts to bf16 (one launch): W_ih, W_hh, fc_W, hidden -> Hall[0]
  const int n0 = 4096 * 512 / 4, n1 = 4096 * 1024 / 4,
            n2 = VOCAB * 1024 / 4, n3 = BATCH * HID / 4;
  const int ncast = n0 + n1 + n2 + n3;
  cast_all_kernel<<<(ncast + 255) / 256, 256, 0, stream>>>(
      W_ih, Wihb, n0, W_hh, Whhb, n1, fc_W, fcWb, n2, hidden, Hall, n3);

  // 2) embedding gather (time-major) + barrier-state zero
  gather_kernel<<<MROWS, 128, 0, stream>>>(inputs, emb, Xbf, bar);

  // 3) GEMM1: Xg = X @ W_ih^T + b_ih + b_hh
  gemm_bt_kernel<<<dim3(4096 / 128, MROWS / 128), 256, 0, stream>>>(
      Xbf, Wihb, b_ih, b_hh, Xg, MROWS, 4096, EMBED);

  // 4) all 48 recurrent steps in ONE persistent kernel (plain launch;
  //    256 WGs x 256 thr at 1 WG/CU are co-resident by capacity)
  lstm_persist4_kernel<<<256, 256, 0, stream>>>(Whhb, Xg, cell, Hall, bar);

  // 5) GEMM2 (256x128 tiles): logits = H_all[1..48] @ fc_W^T + fc_b, scattered
  gemm_bt256_kernel<<<dim3(VOCAB / 128, MROWS / 256), 512, 0, stream>>>(
      Hall + (size_t)BATCH * HID, fcWb, fc_b, out, VOCAB, HID);
}